// Round 2
// baseline (178.731 us; speedup 1.0000x reference)
//
#include <hip/hip_runtime.h>

// Forbid FMA contraction: the reference evaluates each f32 op separately; a
// fused (area_sum - ih*iw) changes rounding and can flip labels at 0.3/0.7.
#pragma clang fp contract(off)

#define N_ANCH   262144
#define N_GT     256
#define MAX_POSK 128
#define TOTALK   256
#define NBINS    2048
#define CAP      2048

// ---------------------------------------------------------------------------
// Threefry-2x32 (exact JAX PRNG). 20 rounds, rotations {13,15,26,6,17,29,16,24}.
// ---------------------------------------------------------------------------
struct TF2 { unsigned a, b; };

__host__ __device__ constexpr unsigned rotl32(unsigned v, int d) {
  return (v << d) | (v >> (32 - d));
}

__host__ __device__ constexpr TF2 tf2x32(unsigned k0, unsigned k1,
                                         unsigned x0, unsigned x1) {
  unsigned ks2 = k0 ^ k1 ^ 0x1BD11BDAu;
  x0 += k0; x1 += k1;
  x0 += x1; x1 = rotl32(x1, 13); x1 ^= x0;
  x0 += x1; x1 = rotl32(x1, 15); x1 ^= x0;
  x0 += x1; x1 = rotl32(x1, 26); x1 ^= x0;
  x0 += x1; x1 = rotl32(x1,  6); x1 ^= x0;
  x0 += k1; x1 += ks2 + 1u;
  x0 += x1; x1 = rotl32(x1, 17); x1 ^= x0;
  x0 += x1; x1 = rotl32(x1, 29); x1 ^= x0;
  x0 += x1; x1 = rotl32(x1, 16); x1 ^= x0;
  x0 += x1; x1 = rotl32(x1, 24); x1 ^= x0;
  x0 += ks2; x1 += k0 + 2u;
  x0 += x1; x1 = rotl32(x1, 13); x1 ^= x0;
  x0 += x1; x1 = rotl32(x1, 15); x1 ^= x0;
  x0 += x1; x1 = rotl32(x1, 26); x1 ^= x0;
  x0 += x1; x1 = rotl32(x1,  6); x1 ^= x0;
  x0 += k0; x1 += k1 + 3u;
  x0 += x1; x1 = rotl32(x1, 17); x1 ^= x0;
  x0 += x1; x1 = rotl32(x1, 29); x1 ^= x0;
  x0 += x1; x1 = rotl32(x1, 16); x1 ^= x0;
  x0 += x1; x1 = rotl32(x1, 24); x1 ^= x0;
  x0 += k1; x1 += ks2 + 4u;
  x0 += x1; x1 = rotl32(x1, 13); x1 ^= x0;
  x0 += x1; x1 = rotl32(x1, 15); x1 ^= x0;
  x0 += x1; x1 = rotl32(x1, 26); x1 ^= x0;
  x0 += x1; x1 = rotl32(x1,  6); x1 ^= x0;
  x0 += ks2; x1 += k0 + 5u;
  return TF2{x0, x1};
}

// jax.random.key(42) -> key data (0, 42).
// Partitionable (modern default) conventions:
//   split(key)  = fold-like: child i = BOTH words of E(key, (0, i))
//   random_bits(key,32,(n,))[i] = E(key, (0, i)).a ^ E(key, (0, i)).b
constexpr unsigned KP0 = tf2x32(0u, 42u, 0u, 0u).a;
constexpr unsigned KP1 = tf2x32(0u, 42u, 0u, 0u).b;
constexpr unsigned KN0 = tf2x32(0u, 42u, 0u, 1u).a;
constexpr unsigned KN1 = tf2x32(0u, 42u, 0u, 1u).b;

__device__ inline unsigned score_bits(unsigned k0, unsigned k1, unsigned i) {
  TF2 r = tf2x32(k0, k1, 0u, i);
  return r.a ^ r.b;
}

// uniform = bitcast((bits>>9)|0x3f800000) - 1.0  => 23-bit value v = bits>>9.
// hist bin = floor(u * 2048) == v >> 12 == bits >> 21  (exact).
// Sort key = (v << 32) | ~idx : desc order == score desc, index asc (== top_k).

// ---------------------------------------------------------------------------
// Device-global scratch — fully rewritten every launch, no cross-call state.
// ---------------------------------------------------------------------------
__device__ int                g_label[N_ANCH];     // -1 / 0 / 1
__device__ int                g_argmax[N_ANCH];
__device__ unsigned           g_sbits[N_ANCH];     // raw 32 random bits (label>=0)
__device__ int                g_hist[2][NBINS];    // [0]=pos, [1]=neg
__device__ int                g_cut[2];            // cutoff bin per class
__device__ int                g_curpos, g_curneg;
__device__ int                g_cnt[2];            // candidate counts
__device__ unsigned long long g_cand[2][CAP];      // (score23<<32)|~idx

// ---------------------------------------------------------------------------
__global__ void k_init() {
  int t = blockIdx.x * blockDim.x + threadIdx.x;
  if (t < 2 * NBINS) (&g_hist[0][0])[t] = 0;
  if (t == 0) { g_cnt[0] = 0; g_cnt[1] = 0; }
}

// One anchor per thread: IoU vs 256 GT boxes (LDS), label, argmax, score+hist.
__global__ __launch_bounds__(256) void k_main(const float4* __restrict__ anchors,
                                              const float4* __restrict__ gt,
                                              const int* __restrict__ ph,
                                              const int* __restrict__ pw) {
  __shared__ float4 s_gt[N_GT];
  __shared__ float  s_garea[N_GT];
  const int tid = threadIdx.x;
  {
    float4 g = gt[tid];
    s_gt[tid] = g;
    s_garea[tid] = (g.z - g.x) * (g.w - g.y);
  }
  __syncthreads();

  const int i = blockIdx.x * 256 + tid;
  const float4 a = anchors[i];
  const float Hf = (float)(*ph);
  const float Wf = (float)(*pw);
  const bool inside = (a.x >= 0.0f) && (a.y >= 0.0f) && (a.z <= Hf) && (a.w <= Wf);
  const float area_a = (a.z - a.x) * (a.w - a.y);

  float best = -1.0f;
  int   arg  = 0;
  #pragma unroll 4
  for (int j = 0; j < N_GT; ++j) {
    const float4 b = s_gt[j];
    float ih = fmaxf(fminf(a.z, b.z) - fmaxf(a.x, b.x), 0.0f);
    float iw = fmaxf(fminf(a.w, b.w) - fmaxf(a.y, b.y), 0.0f);
    float inter = ih * iw;
    float uni = (area_a + s_garea[j]) - inter;
    float iou = inter / fmaxf(uni, 1e-8f);
    if (iou > best) { best = iou; arg = j; }   // strict > : first-max == jnp.argmax
  }

  int lab = -1;
  if (best > 0.7f) lab = 1;
  if (best < 0.3f) lab = 0;
  if (!inside)     lab = -1;

  g_label[i]  = lab;
  g_argmax[i] = arg;

  if (lab >= 0) {
    // branch-free key select avoids pos/neg lane divergence
    const unsigned k0 = (lab == 1) ? KP0 : KN0;
    const unsigned k1 = (lab == 1) ? KP1 : KN1;
    const unsigned sb = score_bits(k0, k1, (unsigned)i);
    g_sbits[i] = sb;
    atomicAdd(&g_hist[lab == 1 ? 0 : 1][sb >> 21], 1);
  }
}

__device__ int find_cut(const int* cs, const int* hist, int K) {
  if (K <= 0) return NBINS;                 // empty candidate set
  int suffix = 0, c = 127;
  for (; c >= 0; --c) {
    if (suffix + cs[c] >= K) break;
    suffix += cs[c];
  }
  if (c < 0) return 0;
  for (int b = c * 16 + 15; b >= c * 16; --b) {
    suffix += hist[b];
    if (suffix >= K) return b;              // largest b with suffix(b) >= K
  }
  return c * 16;
}

__global__ __launch_bounds__(128) void k_select() {
  __shared__ int csp[128], csn[128];
  const int t = threadIdx.x;
  int sp = 0, sn = 0;
  for (int b = t * 16; b < t * 16 + 16; ++b) { sp += g_hist[0][b]; sn += g_hist[1][b]; }
  csp[t] = sp; csn[t] = sn;
  __syncthreads();
  if (t == 0) {
    int total_p = 0, total_n = 0;
    for (int c = 0; c < 128; ++c) { total_p += csp[c]; total_n += csn[c]; }
    int cur_pos = total_p < MAX_POSK ? total_p : MAX_POSK;
    int rem = TOTALK - cur_pos;
    int cur_neg = total_n < rem ? total_n : rem;
    g_curpos = cur_pos;
    g_curneg = cur_neg;
    g_cut[0] = find_cut(csp, g_hist[0], cur_pos);
    g_cut[1] = find_cut(csn, g_hist[1], cur_neg);
  }
}

__global__ __launch_bounds__(256) void k_compact() {
  const int i = blockIdx.x * 256 + threadIdx.x;
  const int lab = g_label[i];
  if (lab < 0) return;
  const int s = (lab == 1) ? 0 : 1;
  const unsigned sb = g_sbits[i];
  if ((int)(sb >> 21) >= g_cut[s]) {
    int p = atomicAdd(&g_cnt[s], 1);
    if (p < CAP)
      g_cand[s][p] = ((unsigned long long)(sb >> 9) << 32) | (unsigned)(~i);
  }
}

// Descending bitonic sort of CAP=2048 u64 keys in LDS, 1024 threads.
__device__ void sort_desc(unsigned long long* keys) {
  const int tid = threadIdx.x;
  for (int k = 2; k <= CAP; k <<= 1) {
    for (int j = k >> 1; j > 0; j >>= 1) {
      for (int t = tid; t < CAP; t += 1024) {
        int ixj = t ^ j;
        if (ixj > t) {
          unsigned long long x = keys[t], y = keys[ixj];
          bool up = (t & k) == 0;
          if (up ? (x < y) : (x > y)) { keys[t] = y; keys[ixj] = x; }
        }
      }
      __syncthreads();
    }
  }
}

__global__ __launch_bounds__(1024) void k_final(int* __restrict__ out) {
  __shared__ unsigned long long keys[CAP];
  const int tid = threadIdx.x;
  const int cur_pos = g_curpos;
  const int cur_neg = g_curneg;

  // positives
  int cA = g_cnt[0]; if (cA > CAP) cA = CAP;
  for (int t = tid; t < CAP; t += 1024) keys[t] = (t < cA) ? g_cand[0][t] : 0ULL;
  __syncthreads();
  sort_desc(keys);
  for (int t = tid; t < cur_pos; t += 1024) {
    int i = (int)(~(unsigned)keys[t]);
    out[t] = i;
    out[TOTALK + t] = 1;
    out[2 * TOTALK + t] = g_argmax[i];
  }
  __syncthreads();

  // negatives
  int cB = g_cnt[1]; if (cB > CAP) cB = CAP;
  for (int t = tid; t < CAP; t += 1024) keys[t] = (t < cB) ? g_cand[1][t] : 0ULL;
  __syncthreads();
  sort_desc(keys);
  for (int t = tid; t < cur_neg; t += 1024) {
    int i = (int)(~(unsigned)keys[t]);
    out[cur_pos + t] = i;
    out[TOTALK + cur_pos + t] = 0;
    out[2 * TOTALK + cur_pos + t] = g_argmax[i];
  }

  // remaining slots = -1
  for (int t = tid; t < TOTALK; t += 1024) {
    if (t >= cur_pos + cur_neg) {
      out[t] = -1;
      out[TOTALK + t] = -1;
      out[2 * TOTALK + t] = -1;
    }
  }
  if (tid == 0) out[3 * TOTALK] = cur_pos;
}

// ---------------------------------------------------------------------------
extern "C" void kernel_launch(void* const* d_in, const int* in_sizes, int n_in,
                              void* d_out, int out_size, void* d_ws, size_t ws_size,
                              hipStream_t stream) {
  (void)in_sizes; (void)n_in; (void)out_size; (void)d_ws; (void)ws_size;
  const float4* anchors = (const float4*)d_in[0];
  const float4* gt      = (const float4*)d_in[1];
  const int*    ph      = (const int*)d_in[2];
  const int*    pw      = (const int*)d_in[3];
  int*          out     = (int*)d_out;

  k_init   <<<(2 * NBINS + 255) / 256, 256, 0, stream>>>();
  k_main   <<<N_ANCH / 256, 256, 0, stream>>>(anchors, gt, ph, pw);
  k_select <<<1, 128, 0, stream>>>();
  k_compact<<<N_ANCH / 256, 256, 0, stream>>>();
  k_final  <<<1, 1024, 0, stream>>>(out);
}

// Round 3
// 115.260 us; speedup vs baseline: 1.5507x; 1.5507x over previous
//
#include <hip/hip_runtime.h>

// Forbid FMA contraction: the reference evaluates each f32 op separately; a
// fused (area_sum - ih*iw) changes rounding and can flip labels at 0.3/0.7.
// (Explicit __builtin_fmaf is still used where WE want fma for approx math.)
#pragma clang fp contract(off)

#define N_ANCH   262144
#define N_GT     256
#define MAX_POSK 128
#define TOTALK   256
#define NBINS    2048
#define CAP      2048
#define BORDCAP  2048

// ---------------------------------------------------------------------------
// Threefry-2x32 (exact JAX PRNG). 20 rounds — VERIFIED bit-exact in round 2.
// ---------------------------------------------------------------------------
struct TF2 { unsigned a, b; };

__host__ __device__ constexpr unsigned rotl32(unsigned v, int d) {
  return (v << d) | (v >> (32 - d));
}

__host__ __device__ constexpr TF2 tf2x32(unsigned k0, unsigned k1,
                                         unsigned x0, unsigned x1) {
  unsigned ks2 = k0 ^ k1 ^ 0x1BD11BDAu;
  x0 += k0; x1 += k1;
  x0 += x1; x1 = rotl32(x1, 13); x1 ^= x0;
  x0 += x1; x1 = rotl32(x1, 15); x1 ^= x0;
  x0 += x1; x1 = rotl32(x1, 26); x1 ^= x0;
  x0 += x1; x1 = rotl32(x1,  6); x1 ^= x0;
  x0 += k1; x1 += ks2 + 1u;
  x0 += x1; x1 = rotl32(x1, 17); x1 ^= x0;
  x0 += x1; x1 = rotl32(x1, 29); x1 ^= x0;
  x0 += x1; x1 = rotl32(x1, 16); x1 ^= x0;
  x0 += x1; x1 = rotl32(x1, 24); x1 ^= x0;
  x0 += ks2; x1 += k0 + 2u;
  x0 += x1; x1 = rotl32(x1, 13); x1 ^= x0;
  x0 += x1; x1 = rotl32(x1, 15); x1 ^= x0;
  x0 += x1; x1 = rotl32(x1, 26); x1 ^= x0;
  x0 += x1; x1 = rotl32(x1,  6); x1 ^= x0;
  x0 += k0; x1 += k1 + 3u;
  x0 += x1; x1 = rotl32(x1, 17); x1 ^= x0;
  x0 += x1; x1 = rotl32(x1, 29); x1 ^= x0;
  x0 += x1; x1 = rotl32(x1, 16); x1 ^= x0;
  x0 += x1; x1 = rotl32(x1, 24); x1 ^= x0;
  x0 += k1; x1 += ks2 + 4u;
  x0 += x1; x1 = rotl32(x1, 13); x1 ^= x0;
  x0 += x1; x1 = rotl32(x1, 15); x1 ^= x0;
  x0 += x1; x1 = rotl32(x1, 26); x1 ^= x0;
  x0 += x1; x1 = rotl32(x1,  6); x1 ^= x0;
  x0 += ks2; x1 += k0 + 5u;
  return TF2{x0, x1};
}

// jax.random.key(42); partitionable threefry (verified):
//   split: child i = both words of E(key,(0,i));  bits[i] = E(key,(0,i)).a ^ .b
constexpr unsigned KP0 = tf2x32(0u, 42u, 0u, 0u).a;
constexpr unsigned KP1 = tf2x32(0u, 42u, 0u, 0u).b;
constexpr unsigned KN0 = tf2x32(0u, 42u, 0u, 1u).a;
constexpr unsigned KN1 = tf2x32(0u, 42u, 0u, 1u).b;

__device__ inline unsigned score_bits(unsigned k0, unsigned k1, unsigned i) {
  TF2 r = tf2x32(k0, k1, 0u, i);
  return r.a ^ r.b;
}

// Exact threshold constants.
// round32(q) > 0.7f  <=> q >= MPOSD  (tie at midpoint rounds up to even 0x3F333334)
// round32(q) >= 0.3f <=> q >= MNEGD  (tie rounds up to even 0x3E99999A)
constexpr double MPOSD = (double)0.7f + 0x1p-25;   // 25-bit mantissa, exact
constexpr double MNEGD = (double)0.3f - 0x1p-26;   // 25-bit mantissa, exact
// Algebraic form: inter >= m*(A+B-inter) <=> inter >= [m/(1+m)]*(A+B)
constexpr float CPF = (float)(MPOSD / (1.0 + MPOSD));
constexpr float CNF = (float)(MNEGD / (1.0 + MNEGD));

// ---------------------------------------------------------------------------
// Device-global scratch — fully rewritten every launch, no cross-call state.
// ---------------------------------------------------------------------------
__device__ unsigned           g_packed[N_ANCH];  // (sbits & ~511) | (label+1)
__device__ int                g_hist[2][NBINS];  // [0]=pos, [1]=neg
__device__ int                g_cut[2];
__device__ int                g_curpos, g_curneg;
__device__ int                g_cnt[2];
__device__ unsigned long long g_cand[2][CAP];    // (score23<<32) | ~idx
__device__ int                g_nbord;
__device__ int                g_bord[BORDCAP];

// ---------------------------------------------------------------------------
__global__ void k_init() {
  int t = blockIdx.x * blockDim.x + threadIdx.x;
  if (t < 2 * NBINS) (&g_hist[0][0])[t] = 0;
  if (t == 2 * NBINS)     { g_cnt[0] = 0; g_cnt[1] = 0; g_nbord = 0; }
}

// One anchor/thread: 256 division-free IoU threshold tests + score + histogram.
__global__ __launch_bounds__(256) void k_main(const float4* __restrict__ anchors,
                                              const float4* __restrict__ gt,
                                              const int* __restrict__ ph,
                                              const int* __restrict__ pw) {
  __shared__ float4 s_gt[N_GT];
  __shared__ float  s_ga[N_GT];
  const int tid = threadIdx.x;
  {
    float4 g = gt[tid];
    s_gt[tid] = g;
    s_ga[tid] = (g.z - g.x) * (g.w - g.y);
  }
  __syncthreads();

  const int i = blockIdx.x * 256 + tid;
  const float4 a = anchors[i];
  const float Hf = (float)(*ph);
  const float Wf = (float)(*pw);
  const bool inside = (a.x >= 0.0f) && (a.y >= 0.0f) && (a.z <= Hf) && (a.w <= Wf);
  const float A = (a.z - a.x) * (a.w - a.y);

  // mr* = max_j (inter - C*(A+B_j)); sign(q - m) == sign(inter - C*(A+B))
  float mrp = -1e30f, mrn = -1e30f;
  #pragma unroll 8
  for (int j = 0; j < N_GT; ++j) {
    const float4 b = s_gt[j];
    float ih = fmaxf(fminf(a.z, b.z) - fmaxf(a.x, b.x), 0.0f);
    float iw = fmaxf(fminf(a.w, b.w) - fmaxf(a.y, b.y), 0.0f);
    float inter = ih * iw;
    float t = A + s_ga[j];
    mrp = fmaxf(mrp, __builtin_fmaf(-CPF, t, inter));
    mrn = fmaxf(mrn, __builtin_fmaf(-CNF, t, inter));
  }

  // Rigorous rounding-error bound is ~2^-23.5*(A+Bmax); use 2^-21 (>=5x slack).
  const float band = 0x1p-21f * (A + 65536.0f);
  const bool pos = mrp > band;   // certainly some q >= MPOSD
  const bool nny = mrn > band;   // certainly some q >= MNEGD (not-negative)
  int lab = pos ? 1 : (nny ? -1 : 0);
  if (!inside) lab = -1;

  unsigned sb = 0u;
  if (lab >= 0) {
    sb = score_bits(lab == 1 ? KP0 : KN0, lab == 1 ? KP1 : KN1, (unsigned)i);
    atomicAdd(&g_hist[lab == 1 ? 0 : 1][sb >> 21], 1);
  }
  g_packed[i] = (sb & ~511u) | (unsigned)(lab + 1);

  // Borderline (|r| within band): defer to exact f64 resolution in k_select.
  if (inside && (fabsf(mrp) <= band || fabsf(mrn) <= band)) {
    int b = atomicAdd(&g_nbord, 1);
    if (b < BORDCAP) g_bord[b] = i;
  }
}

__device__ int find_cut(const int* cs, const int* hist, int K) {
  if (K <= 0) return NBINS;
  int suffix = 0, c = 127;
  for (; c >= 0; --c) {
    if (suffix + cs[c] >= K) break;
    suffix += cs[c];
  }
  if (c < 0) return 0;
  for (int b = c * 16 + 15; b >= c * 16; --b) {
    suffix += hist[b];
    if (suffix >= K) return b;
  }
  return c * 16;
}

// Resolve borderline anchors exactly (f64, exact 25x24-bit product compares),
// patch histogram/labels, then compute totals and cutoff bins.
__global__ __launch_bounds__(128) void k_select(const float4* __restrict__ anchors,
                                                const float4* __restrict__ gt) {
  __shared__ int  csp[128], csn[128];
  __shared__ bool s_p[128], s_n[128];
  const int t = threadIdx.x;

  int nb = g_nbord; if (nb > BORDCAP) nb = BORDCAP;
  for (int b = 0; b < nb; ++b) {
    const int i = g_bord[b];
    const float4 a = anchors[i];
    const float A = (a.z - a.x) * (a.w - a.y);
    bool p = false, nn = false;
    for (int j = t; j < N_GT; j += 128) {
      float4 bb = gt[j];
      float ih = fmaxf(fminf(a.z, bb.z) - fmaxf(a.x, bb.x), 0.0f);
      float iw = fmaxf(fminf(a.w, bb.w) - fmaxf(a.y, bb.y), 0.0f);
      float inter = ih * iw;
      float Bar = (bb.z - bb.x) * (bb.w - bb.y);
      float uni = (A + Bar) - inter;          // exact reference f32 rounding
      double id = (double)inter, ud = (double)uni;
      p  |= (id >= MPOSD * ud);               // exact: 25-bit * 24-bit in f64
      nn |= (id >= MNEGD * ud);
    }
    s_p[t] = p; s_n[t] = nn;
    __syncthreads();
    if (t == 0) {
      bool P = false, NN = false;
      for (int k = 0; k < 128; ++k) { P |= s_p[k]; NN |= s_n[k]; }
      int newlab = P ? 1 : (NN ? -1 : 0);
      unsigned old = g_packed[i];
      int oldlab = (int)(old & 3u) - 1;
      if (newlab != oldlab) {
        if (oldlab >= 0) atomicAdd(&g_hist[oldlab == 1 ? 0 : 1][old >> 21], -1);
        unsigned sb = 0u;
        if (newlab >= 0) {
          sb = score_bits(newlab == 1 ? KP0 : KN0, newlab == 1 ? KP1 : KN1, (unsigned)i);
          atomicAdd(&g_hist[newlab == 1 ? 0 : 1][sb >> 21], 1);
        }
        g_packed[i] = (sb & ~511u) | (unsigned)(newlab + 1);
      }
    }
    __syncthreads();
  }

  int sp = 0, sn = 0;
  for (int b = t * 16; b < t * 16 + 16; ++b) { sp += g_hist[0][b]; sn += g_hist[1][b]; }
  csp[t] = sp; csn[t] = sn;
  __syncthreads();
  if (t == 0) {
    int total_p = 0, total_n = 0;
    for (int c = 0; c < 128; ++c) { total_p += csp[c]; total_n += csn[c]; }
    int cur_pos = total_p < MAX_POSK ? total_p : MAX_POSK;
    int rem = TOTALK - cur_pos;
    int cur_neg = total_n < rem ? total_n : rem;
    g_curpos = cur_pos;
    g_curneg = cur_neg;
    g_cut[0] = find_cut(csp, g_hist[0], cur_pos);
    g_cut[1] = find_cut(csn, g_hist[1], cur_neg);
  }
}

__global__ __launch_bounds__(256) void k_compact() {
  const int i = blockIdx.x * 256 + threadIdx.x;
  const unsigned p = g_packed[i];
  const int lab0 = (int)(p & 3u);
  if (lab0 == 0) return;                      // label -1
  const int s = (lab0 == 2) ? 0 : 1;
  if ((int)(p >> 21) >= g_cut[s]) {
    int q = atomicAdd(&g_cnt[s], 1);
    if (q < CAP)
      g_cand[s][q] = ((unsigned long long)(p >> 9) << 32) | (unsigned)(~i);
  }
}

// Rank-write: for each candidate, rank = #keys greater; out[rank] = idx.
// Keys unique (idx tiebreak) => ranks unique; desc key == score desc, idx asc.
__global__ __launch_bounds__(1024) void k_final(int* __restrict__ out) {
  __shared__ unsigned long long keys[CAP];
  const int tid = threadIdx.x;
  const int cur_pos = g_curpos;
  const int cur_neg = g_curneg;

  for (int t = tid; t < 3 * TOTALK; t += 1024) out[t] = -1;
  if (tid == 0) out[3 * TOTALK] = cur_pos;

  // positives
  int Cp = g_cnt[0]; if (Cp > CAP) Cp = CAP;
  for (int t = tid; t < Cp; t += 1024) keys[t] = g_cand[0][t];
  __syncthreads();
  for (int t = tid; t < Cp; t += 1024) {
    unsigned long long me = keys[t];
    int r = 0;
    for (int u = 0; u < Cp; ++u) r += (keys[u] > me);
    if (r < cur_pos) {
      out[r] = (int)(~(unsigned)me);
      out[TOTALK + r] = 1;
    }
  }
  __syncthreads();

  // negatives
  int Cn = g_cnt[1]; if (Cn > CAP) Cn = CAP;
  for (int t = tid; t < Cn; t += 1024) keys[t] = g_cand[1][t];
  __syncthreads();
  for (int t = tid; t < Cn; t += 1024) {
    unsigned long long me = keys[t];
    int r = 0;
    for (int u = 0; u < Cn; ++u) r += (keys[u] > me);
    if (r < cur_neg) {
      out[cur_pos + r] = (int)(~(unsigned)me);
      out[TOTALK + cur_pos + r] = 0;
    }
  }
}

// Exact argmax (IEEE f32 div, first-max) only for the <=256 selected anchors.
__global__ __launch_bounds__(256) void k_argmax(const float4* __restrict__ anchors,
                                                const float4* __restrict__ gt,
                                                int* __restrict__ out) {
  __shared__ unsigned long long red[256];
  const int slot = blockIdx.x;
  const int j = threadIdx.x;
  const int idx = out[slot];
  if (idx < 0) {
    if (j == 0) out[2 * TOTALK + slot] = -1;
    return;
  }
  const float4 a = anchors[idx];
  const float4 b = gt[j];
  const float A = (a.z - a.x) * (a.w - a.y);
  const float B = (b.z - b.x) * (b.w - b.y);
  float ih = fmaxf(fminf(a.z, b.z) - fmaxf(a.x, b.x), 0.0f);
  float iw = fmaxf(fminf(a.w, b.w) - fmaxf(a.y, b.y), 0.0f);
  float inter = ih * iw;
  float uni = (A + B) - inter;
  float iou = inter / fmaxf(uni, 1e-8f);      // IEEE-exact, matches reference
  // max key = max iou; tie -> smallest j (low word ~j)
  red[j] = ((unsigned long long)__float_as_uint(iou) << 32) | (unsigned)(~j);
  __syncthreads();
  for (int s = 128; s > 0; s >>= 1) {
    if (j < s) { if (red[j + s] > red[j]) red[j] = red[j + s]; }
    __syncthreads();
  }
  if (j == 0) out[2 * TOTALK + slot] = (int)(~(unsigned)red[0]) & 0xFF;
}

// ---------------------------------------------------------------------------
extern "C" void kernel_launch(void* const* d_in, const int* in_sizes, int n_in,
                              void* d_out, int out_size, void* d_ws, size_t ws_size,
                              hipStream_t stream) {
  (void)in_sizes; (void)n_in; (void)out_size; (void)d_ws; (void)ws_size;
  const float4* anchors = (const float4*)d_in[0];
  const float4* gt      = (const float4*)d_in[1];
  const int*    ph      = (const int*)d_in[2];
  const int*    pw      = (const int*)d_in[3];
  int*          out     = (int*)d_out;

  k_init   <<<(2 * NBINS + 256) / 256, 256, 0, stream>>>();
  k_main   <<<N_ANCH / 256, 256, 0, stream>>>(anchors, gt, ph, pw);
  k_select <<<1, 128, 0, stream>>>(anchors, gt);
  k_compact<<<N_ANCH / 256, 256, 0, stream>>>();
  k_final  <<<1, 1024, 0, stream>>>(out);
  k_argmax <<<TOTALK, 256, 0, stream>>>(anchors, gt, out);
}

// Round 4
// 110.797 us; speedup vs baseline: 1.6131x; 1.0403x over previous
//
#include <hip/hip_runtime.h>

// Forbid FMA contraction: the reference evaluates each f32 op separately; a
// fused (A+B) - ih*iw would change rounding and can flip labels at 0.3/0.7.
#pragma clang fp contract(off)

#define N_ANCH   262144
#define N_GT     256
#define MAX_POSK 128
#define TOTALK   256
#define NBINS    2048
#define CAP      2048
#define BORDCAP  2048

// ---------------------------------------------------------------------------
// Threefry-2x32 (exact JAX PRNG). 20 rounds — VERIFIED bit-exact (R2/R3).
// ---------------------------------------------------------------------------
struct TF2 { unsigned a, b; };

__host__ __device__ constexpr unsigned rotl32(unsigned v, int d) {
  return (v << d) | (v >> (32 - d));
}

__host__ __device__ constexpr TF2 tf2x32(unsigned k0, unsigned k1,
                                         unsigned x0, unsigned x1) {
  unsigned ks2 = k0 ^ k1 ^ 0x1BD11BDAu;
  x0 += k0; x1 += k1;
  x0 += x1; x1 = rotl32(x1, 13); x1 ^= x0;
  x0 += x1; x1 = rotl32(x1, 15); x1 ^= x0;
  x0 += x1; x1 = rotl32(x1, 26); x1 ^= x0;
  x0 += x1; x1 = rotl32(x1,  6); x1 ^= x0;
  x0 += k1; x1 += ks2 + 1u;
  x0 += x1; x1 = rotl32(x1, 17); x1 ^= x0;
  x0 += x1; x1 = rotl32(x1, 29); x1 ^= x0;
  x0 += x1; x1 = rotl32(x1, 16); x1 ^= x0;
  x0 += x1; x1 = rotl32(x1, 24); x1 ^= x0;
  x0 += ks2; x1 += k0 + 2u;
  x0 += x1; x1 = rotl32(x1, 13); x1 ^= x0;
  x0 += x1; x1 = rotl32(x1, 15); x1 ^= x0;
  x0 += x1; x1 = rotl32(x1, 26); x1 ^= x0;
  x0 += x1; x1 = rotl32(x1,  6); x1 ^= x0;
  x0 += k0; x1 += k1 + 3u;
  x0 += x1; x1 = rotl32(x1, 17); x1 ^= x0;
  x0 += x1; x1 = rotl32(x1, 29); x1 ^= x0;
  x0 += x1; x1 = rotl32(x1, 16); x1 ^= x0;
  x0 += x1; x1 = rotl32(x1, 24); x1 ^= x0;
  x0 += k1; x1 += ks2 + 4u;
  x0 += x1; x1 = rotl32(x1, 13); x1 ^= x0;
  x0 += x1; x1 = rotl32(x1, 15); x1 ^= x0;
  x0 += x1; x1 = rotl32(x1, 26); x1 ^= x0;
  x0 += x1; x1 = rotl32(x1,  6); x1 ^= x0;
  x0 += ks2; x1 += k0 + 5u;
  return TF2{x0, x1};
}

// jax.random.key(42); partitionable threefry (verified):
//   split: child i = both words of E(key,(0,i));  bits[i] = E(key,(0,i)).a ^ .b
constexpr unsigned KP0 = tf2x32(0u, 42u, 0u, 0u).a;
constexpr unsigned KP1 = tf2x32(0u, 42u, 0u, 0u).b;
constexpr unsigned KN0 = tf2x32(0u, 42u, 0u, 1u).a;
constexpr unsigned KN1 = tf2x32(0u, 42u, 0u, 1u).b;

__device__ inline unsigned score_bits(unsigned k0, unsigned k1, unsigned i) {
  TF2 r = tf2x32(k0, k1, 0u, i);
  return r.a ^ r.b;
}

// Exact threshold constants (verified R3):
// round32(q) > 0.7f  <=> q >= MPOSD ;  round32(q) >= 0.3f <=> q >= MNEGD
constexpr double MPOSD = (double)0.7f + 0x1p-25;
constexpr double MNEGD = (double)0.3f - 0x1p-26;
// inter >= m*(A+B-inter) <=> inter >= [m/(1+m)]*(A+B)
constexpr float CPF = (float)(MPOSD / (1.0 + MPOSD));
constexpr float CNF = (float)(MNEGD / (1.0 + MNEGD));

// ---------------------------------------------------------------------------
// Device-global scratch — fully rewritten every launch, no cross-call state.
// ---------------------------------------------------------------------------
__device__ unsigned           g_packed[N_ANCH];  // (sbits & ~511) | (label+1)
__device__ int                g_hist[2][NBINS];
__device__ int                g_cut[2];
__device__ int                g_curpos, g_curneg;
__device__ int                g_cnt[2];
__device__ unsigned long long g_cand[2][CAP];    // (score23<<32) | ~idx
__device__ int                g_nbord;
__device__ int                g_bord[BORDCAP];

// ---------------------------------------------------------------------------
__global__ void k_init() {
  int t = blockIdx.x * blockDim.x + threadIdx.x;
  if (t < 2 * NBINS) (&g_hist[0][0])[t] = 0;
  if (t == 2 * NBINS) { g_cnt[0] = 0; g_cnt[1] = 0; g_nbord = 0; }
}

__device__ inline void finish_anchor(int i, float4 a, float mp, float mn,
                                     float Hf, float Wf) {
  const float A = (a.z - a.x) * (a.w - a.y);
  const float mrp = mp - CPF * A;     // sign == sign of best q vs MPOSD (+/- band)
  const float mrn = mn - CNF * A;
  const bool inside = (a.x >= 0.0f) && (a.y >= 0.0f) && (a.z <= Hf) && (a.w <= Wf);
  // rounding-error bound ~6*2^-24*(A+B); band = 12*2^-24*(A+65536) >= 2x slack
  const float band = 0x1.8p-21f * (A + 65536.0f);
  const bool pos = mrp > band;
  const bool nny = mrn > band;
  int lab = pos ? 1 : (nny ? -1 : 0);
  if (!inside) lab = -1;

  unsigned sb = 0u;
  if (lab >= 0) {
    sb = score_bits(lab == 1 ? KP0 : KN0, lab == 1 ? KP1 : KN1, (unsigned)i);
    atomicAdd(&g_hist[lab == 1 ? 0 : 1][sb >> 21], 1);
  }
  g_packed[i] = (sb & ~511u) | (unsigned)(lab + 1);

  if (inside && (fabsf(mrp) <= band || fabsf(mrn) <= band)) {
    int b = atomicAdd(&g_nbord, 1);
    if (b < BORDCAP) g_bord[b] = i;
  }
}

// 2 anchors/thread: 256 division-free IoU threshold tests each, score + hist.
__global__ __launch_bounds__(256) void k_main(const float4* __restrict__ anchors,
                                              const float4* __restrict__ gt,
                                              const int* __restrict__ ph,
                                              const int* __restrict__ pw) {
  __shared__ float4 s_gt[N_GT];
  __shared__ float  s_tp[N_GT];   // CPF * B_j
  __shared__ float  s_tn[N_GT];   // CNF * B_j
  const int tid = threadIdx.x;
  {
    float4 g = gt[tid];
    s_gt[tid] = g;
    float B = (g.z - g.x) * (g.w - g.y);
    s_tp[tid] = CPF * B;
    s_tn[tid] = CNF * B;
  }
  __syncthreads();

  const int i0 = blockIdx.x * 512 + tid;
  const int i1 = i0 + 256;
  const float4 a0 = anchors[i0];
  const float4 a1 = anchors[i1];
  const float Hf = (float)(*ph);
  const float Wf = (float)(*pw);

  float mp0 = -1e30f, mn0 = -1e30f, mp1 = -1e30f, mn1 = -1e30f;
  #pragma unroll 4
  for (int j = 0; j < N_GT; ++j) {
    const float4 b = s_gt[j];
    const float tp = s_tp[j];
    const float tn = s_tn[j];
    float ih0 = fmaxf(fminf(a0.z, b.z) - fmaxf(a0.x, b.x), 0.0f);
    float iw0 = fmaxf(fminf(a0.w, b.w) - fmaxf(a0.y, b.y), 0.0f);
    float in0 = ih0 * iw0;
    mp0 = fmaxf(mp0, in0 - tp);
    mn0 = fmaxf(mn0, in0 - tn);
    float ih1 = fmaxf(fminf(a1.z, b.z) - fmaxf(a1.x, b.x), 0.0f);
    float iw1 = fmaxf(fminf(a1.w, b.w) - fmaxf(a1.y, b.y), 0.0f);
    float in1 = ih1 * iw1;
    mp1 = fmaxf(mp1, in1 - tp);
    mn1 = fmaxf(mn1, in1 - tn);
  }
  finish_anchor(i0, a0, mp0, mn0, Hf, Wf);
  finish_anchor(i1, a1, mp1, mn1, Hf, Wf);
}

__device__ int find_cut(const int* cs, const int* hist, int K) {
  if (K <= 0) return NBINS;
  int suffix = 0, c = 127;
  for (; c >= 0; --c) {
    if (suffix + cs[c] >= K) break;
    suffix += cs[c];
  }
  if (c < 0) return 0;
  for (int b = c * 16 + 15; b >= c * 16; --b) {
    suffix += hist[b];
    if (suffix >= K) return b;
  }
  return c * 16;
}

// Border resolve (one anchor per WAVE, ballot-reduced, exact f64 compares),
// then totals + cutoff bins.
__global__ __launch_bounds__(128) void k_select(const float4* __restrict__ anchors,
                                                const float4* __restrict__ gt) {
  __shared__ int csp[128], csn[128];
  const int t = threadIdx.x;
  const int wid = t >> 6, lane = t & 63;

  int nb = g_nbord; if (nb > BORDCAP) nb = BORDCAP;
  for (int b = wid; b < nb; b += 2) {
    const int i = g_bord[b];
    const float4 a = anchors[i];
    const float A = (a.z - a.x) * (a.w - a.y);
    bool p = false, nn = false;
    #pragma unroll
    for (int k = 0; k < 4; ++k) {
      const int j = lane + 64 * k;
      float4 bb = gt[j];
      float ih = fmaxf(fminf(a.z, bb.z) - fmaxf(a.x, bb.x), 0.0f);
      float iw = fmaxf(fminf(a.w, bb.w) - fmaxf(a.y, bb.y), 0.0f);
      float inter = ih * iw;
      float Bar = (bb.z - bb.x) * (bb.w - bb.y);
      float uni = (A + Bar) - inter;          // exact reference f32 rounding
      double id = (double)inter, ud = (double)uni;
      p  |= (id >= MPOSD * ud);               // exact: 25x24-bit products in f64
      nn |= (id >= MNEGD * ud);
    }
    unsigned long long bp = __ballot(p);
    unsigned long long bn = __ballot(nn);
    if (lane == 0) {
      int newlab = bp ? 1 : (bn ? -1 : 0);
      unsigned old = g_packed[i];
      int oldlab = (int)(old & 3u) - 1;
      if (newlab != oldlab) {
        if (oldlab >= 0) atomicAdd(&g_hist[oldlab == 1 ? 0 : 1][old >> 21], -1);
        unsigned sb = 0u;
        if (newlab >= 0) {
          sb = score_bits(newlab == 1 ? KP0 : KN0, newlab == 1 ? KP1 : KN1, (unsigned)i);
          atomicAdd(&g_hist[newlab == 1 ? 0 : 1][sb >> 21], 1);
        }
        g_packed[i] = (sb & ~511u) | (unsigned)(newlab + 1);
      }
    }
  }
  __syncthreads();

  int sp = 0, sn = 0;
  for (int b2 = t * 16; b2 < t * 16 + 16; ++b2) { sp += g_hist[0][b2]; sn += g_hist[1][b2]; }
  csp[t] = sp; csn[t] = sn;
  __syncthreads();
  if (t == 0) {
    int total_p = 0, total_n = 0;
    for (int c = 0; c < 128; ++c) { total_p += csp[c]; total_n += csn[c]; }
    int cur_pos = total_p < MAX_POSK ? total_p : MAX_POSK;
    int rem = TOTALK - cur_pos;
    int cur_neg = total_n < rem ? total_n : rem;
    g_curpos = cur_pos;
    g_curneg = cur_neg;
    g_cut[0] = find_cut(csp, g_hist[0], cur_pos);
    g_cut[1] = find_cut(csn, g_hist[1], cur_neg);
  }
}

__global__ __launch_bounds__(256) void k_compact() {
  const int i = blockIdx.x * 256 + threadIdx.x;
  const unsigned p = g_packed[i];
  const int lab0 = (int)(p & 3u);
  if (lab0 == 0) return;                      // label -1
  const int s = (lab0 == 2) ? 0 : 1;
  if ((int)(p >> 21) >= g_cut[s]) {
    int q = atomicAdd(&g_cnt[s], 1);
    if (q < CAP)
      g_cand[s][q] = ((unsigned long long)(p >> 9) << 32) | (unsigned)(~i);
  }
}

// Rank-write: rank = #keys greater; out[rank] = idx. Keys unique (idx tiebreak)
// => ranks unique; desc key == score desc, idx asc (== lax.top_k order).
__global__ __launch_bounds__(1024) void k_final(int* __restrict__ out) {
  __shared__ unsigned long long keys[CAP];
  const int tid = threadIdx.x;
  const int cur_pos = g_curpos;
  const int cur_neg = g_curneg;

  for (int t = tid; t < 3 * TOTALK; t += 1024) out[t] = -1;
  if (tid == 0) out[3 * TOTALK] = cur_pos;

  int Cp = g_cnt[0]; if (Cp > CAP) Cp = CAP;
  for (int t = tid; t < Cp; t += 1024) keys[t] = g_cand[0][t];
  __syncthreads();
  for (int t = tid; t < Cp; t += 1024) {
    unsigned long long me = keys[t];
    int r = 0;
    for (int u = 0; u < Cp; ++u) r += (keys[u] > me);
    if (r < cur_pos) {
      out[r] = (int)(~(unsigned)me);
      out[TOTALK + r] = 1;
    }
  }
  __syncthreads();

  int Cn = g_cnt[1]; if (Cn > CAP) Cn = CAP;
  for (int t = tid; t < Cn; t += 1024) keys[t] = g_cand[1][t];
  __syncthreads();
  for (int t = tid; t < Cn; t += 1024) {
    unsigned long long me = keys[t];
    int r = 0;
    for (int u = 0; u < Cn; ++u) r += (keys[u] > me);
    if (r < cur_neg) {
      out[cur_pos + r] = (int)(~(unsigned)me);
      out[TOTALK + cur_pos + r] = 0;
    }
  }
}

// Exact argmax (IEEE f32 div, first-max) only for the <=256 selected anchors.
__global__ __launch_bounds__(256) void k_argmax(const float4* __restrict__ anchors,
                                                const float4* __restrict__ gt,
                                                int* __restrict__ out) {
  __shared__ unsigned long long red[256];
  const int slot = blockIdx.x;
  const int j = threadIdx.x;
  const int idx = out[slot];
  if (idx < 0) {
    if (j == 0) out[2 * TOTALK + slot] = -1;
    return;
  }
  const float4 a = anchors[idx];
  const float4 b = gt[j];
  const float A = (a.z - a.x) * (a.w - a.y);
  const float B = (b.z - b.x) * (b.w - b.y);
  float ih = fmaxf(fminf(a.z, b.z) - fmaxf(a.x, b.x), 0.0f);
  float iw = fmaxf(fminf(a.w, b.w) - fmaxf(a.y, b.y), 0.0f);
  float inter = ih * iw;
  float uni = (A + B) - inter;
  float iou = inter / fmaxf(uni, 1e-8f);      // IEEE-exact, matches reference
  red[j] = ((unsigned long long)__float_as_uint(iou) << 32) | (unsigned)(~j);
  __syncthreads();
  for (int s = 128; s > 0; s >>= 1) {
    if (j < s) { if (red[j + s] > red[j]) red[j] = red[j + s]; }
    __syncthreads();
  }
  if (j == 0) out[2 * TOTALK + slot] = (int)(~(unsigned)red[0]) & 0xFF;
}

// ---------------------------------------------------------------------------
extern "C" void kernel_launch(void* const* d_in, const int* in_sizes, int n_in,
                              void* d_out, int out_size, void* d_ws, size_t ws_size,
                              hipStream_t stream) {
  (void)in_sizes; (void)n_in; (void)out_size; (void)d_ws; (void)ws_size;
  const float4* anchors = (const float4*)d_in[0];
  const float4* gt      = (const float4*)d_in[1];
  const int*    ph      = (const int*)d_in[2];
  const int*    pw      = (const int*)d_in[3];
  int*          out     = (int*)d_out;

  k_init   <<<(2 * NBINS + 256) / 256, 256, 0, stream>>>();
  k_main   <<<N_ANCH / 512, 256, 0, stream>>>(anchors, gt, ph, pw);
  k_select <<<1, 128, 0, stream>>>(anchors, gt);
  k_compact<<<N_ANCH / 256, 256, 0, stream>>>();
  k_final  <<<1, 1024, 0, stream>>>(out);
  k_argmax <<<TOTALK, 256, 0, stream>>>(anchors, gt, out);
}